// Round 5
// baseline (236.860 us; speedup 1.0000x reference)
//
#include <hip/hip_runtime.h>
#include <hip/hip_bf16.h>

static constexpr int N_ = 4;
static constexpr int C_ = 9;
static constexpr int D_ = 16;
static constexpr int HWp = 1024 * 1024;
static constexpr int CELLS = D_ * D_ * D_;  // 4096
static constexpr int PT = HWp / 4;          // 262144 float4 positions per image
static constexpr int TPB = 512;
static constexpr int BPI = 256;             // blocks per image

// Fold the 1x1 conv's grid-channel part into the grid, quantize to bf16:
// pre[n][cell] = uint2{ bf16(a1)<<16 | bf16(a0),  bf16(a2) }
//   a_o = sum_c conv_w[o,c] * grid[n,c,cell]
// Error bound: |a| <~ 1.3, bf16 rel err 2^-8 -> abs err <= ~5e-3 << 3.2e-2 threshold.
__global__ __launch_bounds__(256) void fold_grid_kernel(
    const float* __restrict__ grid, const float* __restrict__ cw,
    uint2* __restrict__ pre)
{
    int t = blockIdx.x * blockDim.x + threadIdx.x;
    if (t >= N_ * CELLS) return;
    int n = t >> 12;
    int cell = t & (CELLS - 1);
    const float* g = grid + ((size_t)n * C_) * CELLS + cell;
    float a0 = 0.f, a1 = 0.f, a2 = 0.f;
#pragma unroll
    for (int c = 0; c < C_; ++c) {
        float v = g[(size_t)c * CELLS];
        a0 = fmaf(cw[c], v, a0);
        a1 = fmaf(cw[12 + c], v, a1);
        a2 = fmaf(cw[24 + c], v, a2);
    }
    unsigned short b0 = __bfloat16_as_ushort(__float2bfloat16(a0));
    unsigned short b1 = __bfloat16_as_ushort(__float2bfloat16(a1));
    unsigned short b2 = __bfloat16_as_ushort(__float2bfloat16(a2));
    uint2 v;
    v.x = (unsigned)b0 | ((unsigned)b1 << 16);
    v.y = (unsigned)b2;
    pre[t] = v;
}

__device__ __forceinline__ void unpack3(uint2 w, float& x, float& y, float& z) {
    x = __uint_as_float(w.x << 16);
    y = __uint_as_float(w.x & 0xFFFF0000u);
    z = __uint_as_float(w.y << 16);
}

__device__ __forceinline__ float lerp1(float a, float b, float t) {
    return fmaf(b - a, t, a);
}

__global__ __launch_bounds__(TPB, 6) void slice_kernel(
    const float* __restrict__ guide, const uint2* __restrict__ pre,
    const float* __restrict__ cw, const float* __restrict__ cbias,
    float* __restrict__ out)
{
    __shared__ uint2 sPre[CELLS];  // 32 KB — one image's folded grid (bf16 x,y,z)

    const int n  = blockIdx.x >> 8;        // image index (BPI = 256)
    const int bi = blockIdx.x & (BPI - 1); // block index within image

    // Stage this image's 32 KB table into LDS as uint4 (coalesced b128)
    {
        const uint4* src = (const uint4*)(pre + (size_t)n * CELLS);
        uint4* dst = (uint4*)sPre;
#pragma unroll
        for (int i = 0; i < (CELLS / 2) / TPB; ++i)
            dst[i * TPB + threadIdx.x] = src[i * TPB + threadIdx.x];
    }
    __syncthreads();

    const float4* gR = (const float4*)(guide + (size_t)(n * 3 + 0) * HWp);
    const float4* gG = (const float4*)(guide + (size_t)(n * 3 + 1) * HWp);
    const float4* gB = (const float4*)(guide + (size_t)(n * 3 + 2) * HWp);
    float4* oR = (float4*)(out + (size_t)(n * 3 + 0) * HWp);
    float4* oG = (float4*)(out + (size_t)(n * 3 + 1) * HWp);
    float4* oB = (float4*)(out + (size_t)(n * 3 + 2) * HWp);

    // guide-channel part of the conv + bias (wave-uniform -> scalar loads)
    const float w0r = cw[9],  w0g = cw[10], w0b = cw[11];
    const float w1r = cw[21], w1g = cw[22], w1b = cw[23];
    const float w2r = cw[33], w2g = cw[34], w2b = cw[35];
    const float bi0 = cbias[0], bi1 = cbias[1], bi2 = cbias[2];

    for (int p4 = bi * TPB + threadIdx.x; p4 < PT; p4 += BPI * TPB) {
        float4 r4 = gR[p4];
        float4 g4 = gG[p4];
        float4 b4 = gB[p4];

        float rr[4] = {r4.x, r4.y, r4.z, r4.w};
        float gg[4] = {g4.x, g4.y, g4.z, g4.w};
        float bb[4] = {b4.x, b4.y, b4.z, b4.w};
        float o0[4], o1[4], o2[4];

#pragma unroll
        for (int j = 0; j < 4; ++j) {
            float cr = fminf(fmaxf(rr[j], 0.f), 1.f) * 15.f;
            float cg = fminf(fmaxf(gg[j], 0.f), 1.f) * 15.f;
            float cb = fminf(fmaxf(bb[j], 0.f), 1.f) * 15.f;
            int ir = min((int)cr, 14);   // cr >= 0, trunc == floor
            int ig = min((int)cg, 14);
            int ib = min((int)cb, 14);
            float fr = cr - (float)ir;
            float fg = cg - (float)ig;
            float fb = cb - (float)ib;
            int base = (ir * 16 + ig) * 16 + ib;

            // 8 corners = 8 x ds_read_b64 (8 B cells, b / b+1 adjacent)
            uint2 q000 = sPre[base];
            uint2 q001 = sPre[base + 1];
            uint2 q010 = sPre[base + 16];
            uint2 q011 = sPre[base + 17];
            uint2 q100 = sPre[base + 256];
            uint2 q101 = sPre[base + 257];
            uint2 q110 = sPre[base + 272];
            uint2 q111 = sPre[base + 273];

            float ax, ay, az, bx, by, bz;
            float v00x, v00y, v00z, v01x, v01y, v01z;
            float v10x, v10y, v10z, v11x, v11y, v11z;

            unpack3(q000, ax, ay, az); unpack3(q001, bx, by, bz);
            v00x = lerp1(ax, bx, fb); v00y = lerp1(ay, by, fb); v00z = lerp1(az, bz, fb);
            unpack3(q010, ax, ay, az); unpack3(q011, bx, by, bz);
            v01x = lerp1(ax, bx, fb); v01y = lerp1(ay, by, fb); v01z = lerp1(az, bz, fb);
            unpack3(q100, ax, ay, az); unpack3(q101, bx, by, bz);
            v10x = lerp1(ax, bx, fb); v10y = lerp1(ay, by, fb); v10z = lerp1(az, bz, fb);
            unpack3(q110, ax, ay, az); unpack3(q111, bx, by, bz);
            v11x = lerp1(ax, bx, fb); v11y = lerp1(ay, by, fb); v11z = lerp1(az, bz, fb);

            float v0x = lerp1(v00x, v01x, fg);
            float v0y = lerp1(v00y, v01y, fg);
            float v0z = lerp1(v00z, v01z, fg);
            float v1x = lerp1(v10x, v11x, fg);
            float v1y = lerp1(v10y, v11y, fg);
            float v1z = lerp1(v10z, v11z, fg);

            float vx = lerp1(v0x, v1x, fr);
            float vy = lerp1(v0y, v1y, fr);
            float vz = lerp1(v0z, v1z, fr);

            o0[j] = vx + fmaf(w0r, rr[j], fmaf(w0g, gg[j], fmaf(w0b, bb[j], bi0)));
            o1[j] = vy + fmaf(w1r, rr[j], fmaf(w1g, gg[j], fmaf(w1b, bb[j], bi1)));
            o2[j] = vz + fmaf(w2r, rr[j], fmaf(w2g, gg[j], fmaf(w2b, bb[j], bi2)));
        }

        oR[p4] = make_float4(o0[0], o0[1], o0[2], o0[3]);
        oG[p4] = make_float4(o1[0], o1[1], o1[2], o1[3]);
        oB[p4] = make_float4(o2[0], o2[1], o2[2], o2[3]);
    }
}

extern "C" void kernel_launch(void* const* d_in, const int* in_sizes, int n_in,
                              void* d_out, int out_size, void* d_ws, size_t ws_size,
                              hipStream_t stream) {
    const float* grid  = (const float*)d_in[0];
    const float* guide = (const float*)d_in[1];
    const float* cw    = (const float*)d_in[2];
    const float* cb    = (const float*)d_in[3];
    float* out = (float*)d_out;
    uint2* pre = (uint2*)d_ws;  // N_*CELLS uint2 = 128 KB

    fold_grid_kernel<<<(N_ * CELLS + 255) / 256, 256, 0, stream>>>(grid, cw, pre);

    slice_kernel<<<N_ * BPI, TPB, 0, stream>>>(guide, pre, cw, cb, out);
}

// Round 6
// 114.544 us; speedup vs baseline: 2.0678x; 2.0678x over previous
//
#include <hip/hip_runtime.h>
#include <hip/hip_bf16.h>

static constexpr int N_ = 4;
static constexpr int C_ = 9;
static constexpr int D_ = 16;
static constexpr int HWp = 1024 * 1024;
static constexpr int CELLS = D_ * D_ * D_;  // 4096
static constexpr int PT = HWp / 4;          // 262144 float4 positions per image
static constexpr int TPB = 512;
static constexpr int BPI = 256;             // blocks per image; each block owns 1024 contiguous f4

__device__ __forceinline__ void unpack3(uint2 w, float& x, float& y, float& z) {
    x = __uint_as_float(w.x << 16);
    y = __uint_as_float(w.x & 0xFFFF0000u);
    z = __uint_as_float(w.y << 16);
}

__device__ __forceinline__ float lerp1(float a, float b, float t) {
    return fmaf(b - a, t, a);
}

// Single self-contained kernel: fold conv_w into a per-block bf16 LDS table
// (linear in grid => exact algebraic fold; bf16 quant err <= ~5e-3 << 3.2e-2),
// then trilinear-gather from LDS while streaming guide->out contiguously.
__global__ __launch_bounds__(TPB) void slice_kernel(
    const float* __restrict__ grid, const float* __restrict__ guide,
    const float* __restrict__ cw, const float* __restrict__ cbias,
    float* __restrict__ out)
{
    __shared__ uint2 sPre[CELLS];  // 32 KB: bf16 x,y,z per cell

    const int n  = blockIdx.x >> 8;        // image
    const int bi = blockIdx.x & (BPI - 1); // tile within image

    // ---- In-block fold: 8 cells per thread, coalesced dword reads of grid ----
    {
        const float* g = grid + (size_t)n * C_ * CELLS;
#pragma unroll
        for (int k = 0; k < CELLS / TPB; ++k) {
            int cell = k * TPB + threadIdx.x;
            float a0 = 0.f, a1 = 0.f, a2 = 0.f;
#pragma unroll
            for (int c = 0; c < C_; ++c) {
                float v = g[(size_t)c * CELLS + cell];
                a0 = fmaf(cw[c], v, a0);
                a1 = fmaf(cw[12 + c], v, a1);
                a2 = fmaf(cw[24 + c], v, a2);
            }
            unsigned short b0 = __bfloat16_as_ushort(__float2bfloat16(a0));
            unsigned short b1 = __bfloat16_as_ushort(__float2bfloat16(a1));
            unsigned short b2 = __bfloat16_as_ushort(__float2bfloat16(a2));
            uint2 v;
            v.x = (unsigned)b0 | ((unsigned)b1 << 16);
            v.y = (unsigned)b2;
            sPre[cell] = v;
        }
    }
    __syncthreads();

    const float4* gR = (const float4*)(guide + (size_t)(n * 3 + 0) * HWp);
    const float4* gG = (const float4*)(guide + (size_t)(n * 3 + 1) * HWp);
    const float4* gB = (const float4*)(guide + (size_t)(n * 3 + 2) * HWp);
    float4* oR = (float4*)(out + (size_t)(n * 3 + 0) * HWp);
    float4* oG = (float4*)(out + (size_t)(n * 3 + 1) * HWp);
    float4* oB = (float4*)(out + (size_t)(n * 3 + 2) * HWp);

    const float w0r = cw[9],  w0g = cw[10], w0b = cw[11];
    const float w1r = cw[21], w1g = cw[22], w1b = cw[23];
    const float w2r = cw[33], w2g = cw[34], w2b = cw[35];
    const float bi0 = cbias[0], bi1 = cbias[1], bi2 = cbias[2];

    const int base0 = bi * (PT / BPI);  // 1024 contiguous f4 per block

#pragma unroll
    for (int it = 0; it < (PT / BPI) / TPB; ++it) {
        const int p4 = base0 + it * TPB + threadIdx.x;
        float4 r4 = gR[p4];
        float4 g4 = gG[p4];
        float4 b4 = gB[p4];

        float rr[4] = {r4.x, r4.y, r4.z, r4.w};
        float gg[4] = {g4.x, g4.y, g4.z, g4.w};
        float bb[4] = {b4.x, b4.y, b4.z, b4.w};
        float o0[4], o1[4], o2[4];

#pragma unroll
        for (int j = 0; j < 4; ++j) {
            float cr = fminf(fmaxf(rr[j], 0.f), 1.f) * 15.f;
            float cg = fminf(fmaxf(gg[j], 0.f), 1.f) * 15.f;
            float cb = fminf(fmaxf(bb[j], 0.f), 1.f) * 15.f;
            int ir = min((int)cr, 14);
            int ig = min((int)cg, 14);
            int ib = min((int)cb, 14);
            float fr = cr - (float)ir;
            float fg = cg - (float)ig;
            float fb = cb - (float)ib;
            int base = (ir * 16 + ig) * 16 + ib;

            uint2 q000 = sPre[base];
            uint2 q001 = sPre[base + 1];
            uint2 q010 = sPre[base + 16];
            uint2 q011 = sPre[base + 17];
            uint2 q100 = sPre[base + 256];
            uint2 q101 = sPre[base + 257];
            uint2 q110 = sPre[base + 272];
            uint2 q111 = sPre[base + 273];

            float ax, ay, az, bx, by, bz;
            float v00x, v00y, v00z, v01x, v01y, v01z;
            float v10x, v10y, v10z, v11x, v11y, v11z;

            unpack3(q000, ax, ay, az); unpack3(q001, bx, by, bz);
            v00x = lerp1(ax, bx, fb); v00y = lerp1(ay, by, fb); v00z = lerp1(az, bz, fb);
            unpack3(q010, ax, ay, az); unpack3(q011, bx, by, bz);
            v01x = lerp1(ax, bx, fb); v01y = lerp1(ay, by, fb); v01z = lerp1(az, bz, fb);
            unpack3(q100, ax, ay, az); unpack3(q101, bx, by, bz);
            v10x = lerp1(ax, bx, fb); v10y = lerp1(ay, by, fb); v10z = lerp1(az, bz, fb);
            unpack3(q110, ax, ay, az); unpack3(q111, bx, by, bz);
            v11x = lerp1(ax, bx, fb); v11y = lerp1(ay, by, fb); v11z = lerp1(az, bz, fb);

            float v0x = lerp1(v00x, v01x, fg);
            float v0y = lerp1(v00y, v01y, fg);
            float v0z = lerp1(v00z, v01z, fg);
            float v1x = lerp1(v10x, v11x, fg);
            float v1y = lerp1(v10y, v11y, fg);
            float v1z = lerp1(v10z, v11z, fg);

            float vx = lerp1(v0x, v1x, fr);
            float vy = lerp1(v0y, v1y, fr);
            float vz = lerp1(v0z, v1z, fr);

            o0[j] = vx + fmaf(w0r, rr[j], fmaf(w0g, gg[j], fmaf(w0b, bb[j], bi0)));
            o1[j] = vy + fmaf(w1r, rr[j], fmaf(w1g, gg[j], fmaf(w1b, bb[j], bi1)));
            o2[j] = vz + fmaf(w2r, rr[j], fmaf(w2g, gg[j], fmaf(w2b, bb[j], bi2)));
        }

        oR[p4] = make_float4(o0[0], o0[1], o0[2], o0[3]);
        oG[p4] = make_float4(o1[0], o1[1], o1[2], o1[3]);
        oB[p4] = make_float4(o2[0], o2[1], o2[2], o2[3]);
    }
}

extern "C" void kernel_launch(void* const* d_in, const int* in_sizes, int n_in,
                              void* d_out, int out_size, void* d_ws, size_t ws_size,
                              hipStream_t stream) {
    const float* grid  = (const float*)d_in[0];
    const float* guide = (const float*)d_in[1];
    const float* cw    = (const float*)d_in[2];
    const float* cb    = (const float*)d_in[3];
    float* out = (float*)d_out;

    slice_kernel<<<N_ * BPI, TPB, 0, stream>>>(grid, guide, cw, cb, out);
}